// Round 3
// baseline (1283.519 us; speedup 1.0000x reference)
//
#include <hip/hip_runtime.h>
#include <math.h>

// Problem constants
#define B_   16
#define LU_  2048
#define LV_  2048
#define D_   1024
#define NTC_ (LV_ / 256)   // 8 v-tiles of 256 (stats granularity)
#define MB_  (1024ull * 1024ull)

typedef __attribute__((ext_vector_type(8))) short bf16x8;
typedef __attribute__((ext_vector_type(4))) float f32x4;

__device__ __forceinline__ unsigned short f2bf(float x) {
    unsigned int u = __builtin_bit_cast(unsigned int, x);
    u += 0x7fffu + ((u >> 16) & 1u);          // RNE
    return (unsigned short)(u >> 16);
}
__device__ __forceinline__ float bf2f(unsigned short h) {
    unsigned int u = ((unsigned int)h) << 16;
    return __builtin_bit_cast(float, u);
}

__device__ __forceinline__ void gload_lds16(const void* g, void* l) {
    __builtin_amdgcn_global_load_lds(
        (const __attribute__((address_space(1))) void*)g,
        (__attribute__((address_space(3))) void*)l, 16, 0, 0);
}

// tile gate: my stage loads landed, then block-wide barrier
__device__ __forceinline__ void gate_vm0() {
    asm volatile("s_waitcnt vmcnt(0)" ::: "memory");
    __builtin_amdgcn_s_barrier();
    asm volatile("" ::: "memory");
}

// ---------------------------------------------------------------------------
// K0: per-batch valid length from mask, with byte-vs-int32 layout detection.
__global__ void lengths_kernel(const void* __restrict__ mask, int* __restrict__ lengths) {
    __shared__ int viol;
    __shared__ int cnt[B_];
    const int t = threadIdx.x;
    if (t == 0) viol = 0;
    if (t < B_) cnt[t] = 0;
    __syncthreads();
    const unsigned char* mb = (const unsigned char*)mask;
    int local = 0;
    for (int i = t; i < B_ * LV_ - 1; i += 256) {
        if (((i + 1) % LV_) != 0) {
            if (mb[i] != 0 && mb[i + 1] == 0) local++;
        }
    }
    if (local) atomicAdd(&viol, local);
    __syncthreads();
    const bool is_i32 = (viol > 0);
    const int b = t >> 4, s = t & 15;
    int c = 0;
    if (is_i32) {
        const int* mi = (const int*)mask;
        for (int v2 = s; v2 < LV_; v2 += 16) c += (mi[b * LV_ + v2] == 0) ? 1 : 0;
    } else {
        for (int v2 = s; v2 < LV_; v2 += 16) c += (mb[b * LV_ + v2] == 0) ? 1 : 0;
    }
    atomicAdd(&cnt[b], c);
    __syncthreads();
    if (t < B_) lengths[t] = cnt[t];
}

// ---------------------------------------------------------------------------
// K1: fp32 -> bf16 hi/lo split (elementwise, 8 elems/thread, grid-stride)
__global__ __launch_bounds__(256) void split_kernel(
    const float* __restrict__ X, unsigned short* __restrict__ hi,
    unsigned short* __restrict__ lo, long n8) {
    const long stride = (long)gridDim.x * 256;
    for (long i = (long)blockIdx.x * 256 + threadIdx.x; i < n8; i += stride) {
        float4 x0 = ((const float4*)X)[i * 2];
        float4 x1 = ((const float4*)X)[i * 2 + 1];
        float xv[8] = {x0.x, x0.y, x0.z, x0.w, x1.x, x1.y, x1.z, x1.w};
        bf16x8 h, l;
#pragma unroll
        for (int j = 0; j < 8; j++) {
            unsigned short hh = f2bf(xv[j]);
            h[j] = (short)hh;
            l[j] = (short)f2bf(xv[j] - bf2f(hh));
        }
        ((bf16x8*)hi)[i] = h;
        ((bf16x8*)lo)[i] = l;
    }
}

// ---------------------------------------------------------------------------
// 256x256-tile 8-wave pipelined GEMM core (hi/lo virtual-K64 rows).
// LDS: sA[2][256][64], sB[2][256][64] shorts = 128 KiB dynamic.
// Row layout: [hi k..k+31 | lo k..k+31], chunk swizzle cd = cl ^ (r&7).
// Stage-ahead-1 via raw s_barrier + vmcnt(0) gate; B-frags reg-cached per tile.

// K2: Y = relu(X @ W^T + b) -> bf16 hi/lo
__global__ __launch_bounds__(512, 1) void proj_kernel(
    const unsigned short* __restrict__ Xh, const unsigned short* __restrict__ Xl,
    const unsigned short* __restrict__ Wh, const unsigned short* __restrict__ Wl,
    const float* __restrict__ bias,
    unsigned short* __restrict__ Yhi, unsigned short* __restrict__ Ylo) {
    extern __shared__ unsigned short lds[];
    unsigned short* sA = lds;            // [buf][256][64]: buf*16384
    unsigned short* sB = lds + 32768;
    const int t = threadIdx.x, lane = t & 63, w = t >> 6;
    const int wm = w >> 2, wn = w & 3;
    const int fr = lane & 15, fg = lane >> 4;
    const int row0 = blockIdx.x * 256, col0 = blockIdx.y * 256;

    // staging sources (4 issues per operand), at k=0
    const unsigned short* srcA[4];
    const unsigned short* srcB[4];
    int dstoff[4];
#pragma unroll
    for (int i = 0; i < 4; i++) {
        const int f = i * 512 + t;
        const int r = f >> 3, cd = f & 7;
        const int cl = cd ^ (r & 7);
        const int koff = (cl & 3) * 8;
        srcA[i] = ((cl < 4) ? Xh : Xl) + (size_t)(row0 + r) * D_ + koff;
        srcB[i] = ((cl < 4) ? Wh : Wl) + (size_t)(col0 + r) * D_ + koff;
        dstoff[i] = (i * 512 + w * 64) * 8;   // wave-uniform
    }
    // fragment read offsets
    int aoff[8][2], boff[4][2];
#pragma unroll
    for (int m = 0; m < 8; m++) {
        const int r = wm * 128 + m * 16 + fr;
#pragma unroll
        for (int p = 0; p < 2; p++) aoff[m][p] = r * 64 + ((p * 4 + fg) ^ (r & 7)) * 8;
    }
#pragma unroll
    for (int n = 0; n < 4; n++) {
        const int r = wn * 64 + n * 16 + fr;
#pragma unroll
        for (int p = 0; p < 2; p++) boff[n][p] = r * 64 + ((p * 4 + fg) ^ (r & 7)) * 8;
    }

    const f32x4 fzero = {0.f, 0.f, 0.f, 0.f};
    f32x4 acc[8][4];
#pragma unroll
    for (int m = 0; m < 8; m++)
#pragma unroll
        for (int n = 0; n < 4; n++) acc[m][n] = fzero;

    // prologue: stage tile 0 into buf 0
#pragma unroll
    for (int i = 0; i < 4; i++) {
        gload_lds16(srcA[i], &sA[dstoff[i]]);
        gload_lds16(srcB[i], &sB[dstoff[i]]);
    }

    for (int T = 0; T < 32; ++T) {
        const int buf = T & 1;
        gate_vm0();
        if (T < 31) {
            const int nb = (buf ^ 1) * 16384;
            const int kadd = (T + 1) * 32;
#pragma unroll
            for (int i = 0; i < 4; i++) {
                gload_lds16(srcA[i] + kadd, &sA[nb + dstoff[i]]);
                gload_lds16(srcB[i] + kadd, &sB[nb + dstoff[i]]);
            }
        }
        const int bb = buf * 16384;
        bf16x8 breg[4][2];
#pragma unroll
        for (int n = 0; n < 4; n++) {
            breg[n][0] = *(const bf16x8*)&sB[bb + boff[n][0]];
            breg[n][1] = *(const bf16x8*)&sB[bb + boff[n][1]];
        }
#pragma unroll
        for (int q = 0; q < 4; q++) {
            const bf16x8 a0h = *(const bf16x8*)&sA[bb + aoff[2 * q][0]];
            const bf16x8 a0l = *(const bf16x8*)&sA[bb + aoff[2 * q][1]];
            const bf16x8 a1h = *(const bf16x8*)&sA[bb + aoff[2 * q + 1][0]];
            const bf16x8 a1l = *(const bf16x8*)&sA[bb + aoff[2 * q + 1][1]];
            __builtin_amdgcn_s_setprio(1);
#pragma unroll
            for (int n = 0; n < 4; n++) {
                acc[2 * q][n] = __builtin_amdgcn_mfma_f32_16x16x32_bf16(a0h, breg[n][0], acc[2 * q][n], 0, 0, 0);
                acc[2 * q][n] = __builtin_amdgcn_mfma_f32_16x16x32_bf16(a0h, breg[n][1], acc[2 * q][n], 0, 0, 0);
                acc[2 * q][n] = __builtin_amdgcn_mfma_f32_16x16x32_bf16(a0l, breg[n][0], acc[2 * q][n], 0, 0, 0);
                acc[2 * q + 1][n] = __builtin_amdgcn_mfma_f32_16x16x32_bf16(a1h, breg[n][0], acc[2 * q + 1][n], 0, 0, 0);
                acc[2 * q + 1][n] = __builtin_amdgcn_mfma_f32_16x16x32_bf16(a1h, breg[n][1], acc[2 * q + 1][n], 0, 0, 0);
                acc[2 * q + 1][n] = __builtin_amdgcn_mfma_f32_16x16x32_bf16(a1l, breg[n][0], acc[2 * q + 1][n], 0, 0, 0);
            }
            __builtin_amdgcn_s_setprio(0);
        }
    }

    // epilogue: relu + hi/lo split store
#pragma unroll
    for (int n = 0; n < 4; n++) {
        const int col = col0 + wn * 64 + n * 16 + fr;
        const float bv = bias[col];
#pragma unroll
        for (int m = 0; m < 8; m++) {
#pragma unroll
            for (int j = 0; j < 4; j++) {
                const int row = row0 + wm * 128 + m * 16 + fg * 4 + j;
                float y = fmaxf(acc[m][n][j] + bv, 0.f);
                const unsigned short hh = f2bf(y);
                const size_t idx = (size_t)row * D_ + col;
                Yhi[idx] = hh;
                Ylo[idx] = f2bf(y - bf2f(hh));
            }
        }
    }
}

// ---------------------------------------------------------------------------
// K3: v fp32 [B][LV][D] -> vT bf16 [B][D][LV]
__global__ __launch_bounds__(256) void transpose_v_kernel(
    const float* __restrict__ V, unsigned short* __restrict__ VT) {
    __shared__ unsigned short s[64 * 72];
    const int b = blockIdx.z;
    const int v0 = blockIdx.x * 64, d0 = blockIdx.y * 64;
    const int t = threadIdx.x;
    {
        const int r = t >> 2, q = (t & 3) * 16;
        const float* src = V + ((size_t)b * LV_ + v0 + r) * D_ + d0 + q;
#pragma unroll
        for (int i = 0; i < 4; i++) {
            float4 x = ((const float4*)src)[i];
            s[r * 72 + q + i * 4 + 0] = f2bf(x.x);
            s[r * 72 + q + i * 4 + 1] = f2bf(x.y);
            s[r * 72 + q + i * 4 + 2] = f2bf(x.z);
            s[r * 72 + q + i * 4 + 3] = f2bf(x.w);
        }
    }
    __syncthreads();
    {
        const int d = t >> 2, vq = (t & 3) * 16;
        bf16x8 t0, t1;
#pragma unroll
        for (int j = 0; j < 8; j++) t0[j] = (short)s[(vq + j) * 72 + d];
#pragma unroll
        for (int j = 0; j < 8; j++) t1[j] = (short)s[(vq + 8 + j) * 72 + d];
        unsigned short* dst = VT + ((size_t)b * D_ + d0 + d) * LV_ + v0 + vq;
        ((bf16x8*)dst)[0] = t0;
        ((bf16x8*)dst)[1] = t1;
    }
}

// ---------------------------------------------------------------------------
// K4: logits, 256x256 tile, same pipelined core; per-tile softmax stats.
__global__ __launch_bounds__(512, 1) void attn_logits_kernel(
    const unsigned short* __restrict__ Uh, const unsigned short* __restrict__ Ul,
    const unsigned short* __restrict__ Vh, const unsigned short* __restrict__ Vl,
    const int* __restrict__ lengths,
    unsigned short* __restrict__ Pp, float* __restrict__ m_used,
    float* __restrict__ Z_used) {
    extern __shared__ unsigned short lds[];
    unsigned short* sA = lds;
    unsigned short* sB = lds + 32768;
    const int b = blockIdx.z, ut = blockIdx.x, vt = blockIdx.y;
    const int t = threadIdx.x, lane = t & 63, w = t >> 6;
    const int wm = w >> 2, wn = w & 3;
    const int fr = lane & 15, fg = lane >> 4;
    const int length = lengths[b];
    const int row0 = ut * 256, col0 = vt * 256;

    if (col0 >= length) {   // fully-masked tile
        const bf16x8 zv = {0, 0, 0, 0, 0, 0, 0, 0};
#pragma unroll
        for (int i = 0; i < 16; i++) {
            const int f = i * 512 + t;
            const int r = f >> 5, c8 = (f & 31) * 8;
            *(bf16x8*)&Pp[(size_t)(b * LU_ + row0 + r) * LV_ + col0 + c8] = zv;
        }
        if (t < 256) {
            const size_t row = (size_t)b * LU_ + row0 + t;
            m_used[row * NTC_ + vt] = -__builtin_inff();
            Z_used[row * NTC_ + vt] = 0.f;
        }
        return;
    }

    const unsigned short* srcA[4];
    const unsigned short* srcB[4];
    int dstoff[4];
#pragma unroll
    for (int i = 0; i < 4; i++) {
        const int f = i * 512 + t;
        const int r = f >> 3, cd = f & 7;
        const int cl = cd ^ (r & 7);
        const int koff = (cl & 3) * 8;
        srcA[i] = ((cl < 4) ? Uh : Ul) + ((size_t)b * LU_ + row0 + r) * D_ + koff;
        srcB[i] = ((cl < 4) ? Vh : Vl) + ((size_t)b * LV_ + col0 + r) * D_ + koff;
        dstoff[i] = (i * 512 + w * 64) * 8;
    }
    int aoff[8][2], boff[4][2];
#pragma unroll
    for (int m = 0; m < 8; m++) {
        const int r = wm * 128 + m * 16 + fr;
#pragma unroll
        for (int p = 0; p < 2; p++) aoff[m][p] = r * 64 + ((p * 4 + fg) ^ (r & 7)) * 8;
    }
#pragma unroll
    for (int n = 0; n < 4; n++) {
        const int r = wn * 64 + n * 16 + fr;
#pragma unroll
        for (int p = 0; p < 2; p++) boff[n][p] = r * 64 + ((p * 4 + fg) ^ (r & 7)) * 8;
    }

    const f32x4 fzero = {0.f, 0.f, 0.f, 0.f};
    f32x4 acc[8][4];
#pragma unroll
    for (int m = 0; m < 8; m++)
#pragma unroll
        for (int n = 0; n < 4; n++) acc[m][n] = fzero;

#pragma unroll
    for (int i = 0; i < 4; i++) {
        gload_lds16(srcA[i], &sA[dstoff[i]]);
        gload_lds16(srcB[i], &sB[dstoff[i]]);
    }

    for (int T = 0; T < 32; ++T) {
        const int buf = T & 1;
        gate_vm0();
        if (T < 31) {
            const int nb = (buf ^ 1) * 16384;
            const int kadd = (T + 1) * 32;
#pragma unroll
            for (int i = 0; i < 4; i++) {
                gload_lds16(srcA[i] + kadd, &sA[nb + dstoff[i]]);
                gload_lds16(srcB[i] + kadd, &sB[nb + dstoff[i]]);
            }
        }
        const int bb = buf * 16384;
        bf16x8 breg[4][2];
#pragma unroll
        for (int n = 0; n < 4; n++) {
            breg[n][0] = *(const bf16x8*)&sB[bb + boff[n][0]];
            breg[n][1] = *(const bf16x8*)&sB[bb + boff[n][1]];
        }
#pragma unroll
        for (int q = 0; q < 4; q++) {
            const bf16x8 a0h = *(const bf16x8*)&sA[bb + aoff[2 * q][0]];
            const bf16x8 a0l = *(const bf16x8*)&sA[bb + aoff[2 * q][1]];
            const bf16x8 a1h = *(const bf16x8*)&sA[bb + aoff[2 * q + 1][0]];
            const bf16x8 a1l = *(const bf16x8*)&sA[bb + aoff[2 * q + 1][1]];
            __builtin_amdgcn_s_setprio(1);
#pragma unroll
            for (int n = 0; n < 4; n++) {
                acc[2 * q][n] = __builtin_amdgcn_mfma_f32_16x16x32_bf16(a0h, breg[n][0], acc[2 * q][n], 0, 0, 0);
                acc[2 * q][n] = __builtin_amdgcn_mfma_f32_16x16x32_bf16(a0h, breg[n][1], acc[2 * q][n], 0, 0, 0);
                acc[2 * q][n] = __builtin_amdgcn_mfma_f32_16x16x32_bf16(a0l, breg[n][0], acc[2 * q][n], 0, 0, 0);
                acc[2 * q + 1][n] = __builtin_amdgcn_mfma_f32_16x16x32_bf16(a1h, breg[n][0], acc[2 * q + 1][n], 0, 0, 0);
                acc[2 * q + 1][n] = __builtin_amdgcn_mfma_f32_16x16x32_bf16(a1h, breg[n][1], acc[2 * q + 1][n], 0, 0, 0);
                acc[2 * q + 1][n] = __builtin_amdgcn_mfma_f32_16x16x32_bf16(a1l, breg[n][0], acc[2 * q + 1][n], 0, 0, 0);
            }
            __builtin_amdgcn_s_setprio(0);
        }
    }

    // ---- per-tile softmax stats (tile = 256 rows x 256 cols) ----
    __syncthreads();
    float* sMax = (float*)sB;            // [256][4]
    float* sSum = sMax + 1024;           // [256][4]

    // pass 1: per-wave (64-col) max per row
#pragma unroll
    for (int m = 0; m < 8; m++) {
        float mt[4] = {-__builtin_inff(), -__builtin_inff(), -__builtin_inff(), -__builtin_inff()};
#pragma unroll
        for (int n = 0; n < 4; n++) {
            const int col = col0 + wn * 64 + n * 16 + fr;
            if (col < length) {
#pragma unroll
                for (int j = 0; j < 4; j++) mt[j] = fmaxf(mt[j], acc[m][n][j]);
            }
        }
#pragma unroll
        for (int d = 1; d < 16; d <<= 1) {
#pragma unroll
            for (int j = 0; j < 4; j++) mt[j] = fmaxf(mt[j], __shfl_xor(mt[j], d));
        }
        if (fr == 0) {
#pragma unroll
            for (int j = 0; j < 4; j++)
                sMax[(wm * 128 + m * 16 + fg * 4 + j) * 4 + wn] = mt[j];
        }
    }
    __syncthreads();
    // pass 2: p = exp(acc - m_row), store P', accumulate row sums
#pragma unroll
    for (int m = 0; m < 8; m++) {
        float mrow[4], rs[4] = {0.f, 0.f, 0.f, 0.f};
#pragma unroll
        for (int j = 0; j < 4; j++) {
            const int rl = wm * 128 + m * 16 + fg * 4 + j;
            mrow[j] = fmaxf(fmaxf(sMax[rl * 4 + 0], sMax[rl * 4 + 1]),
                            fmaxf(sMax[rl * 4 + 2], sMax[rl * 4 + 3]));
        }
#pragma unroll
        for (int n = 0; n < 4; n++) {
            const int col = col0 + wn * 64 + n * 16 + fr;
            const bool valid = (col < length);
#pragma unroll
            for (int j = 0; j < 4; j++) {
                const float p = valid ? __expf(acc[m][n][j] - mrow[j]) : 0.f;
                rs[j] += p;
                const size_t row = (size_t)b * LU_ + row0 + wm * 128 + m * 16 + fg * 4 + j;
                Pp[row * LV_ + col] = f2bf(p);
            }
        }
#pragma unroll
        for (int d = 1; d < 16; d <<= 1) {
#pragma unroll
            for (int j = 0; j < 4; j++) rs[j] += __shfl_xor(rs[j], d);
        }
        if (fr == 0) {
#pragma unroll
            for (int j = 0; j < 4; j++)
                sSum[(wm * 128 + m * 16 + fg * 4 + j) * 4 + wn] = rs[j];
        }
    }
    __syncthreads();
    if (t < 256) {
        const float m_t = fmaxf(fmaxf(sMax[t * 4 + 0], sMax[t * 4 + 1]),
                                fmaxf(sMax[t * 4 + 2], sMax[t * 4 + 3]));
        const float z = sSum[t * 4 + 0] + sSum[t * 4 + 1] + sSum[t * 4 + 2] + sSum[t * 4 + 3];
        const size_t row = (size_t)b * LU_ + row0 + t;
        m_used[row * NTC_ + vt] = m_t;
        Z_used[row * NTC_ + vt] = z;
    }
}

// ---------------------------------------------------------------------------
// K5: combine per-tile stats -> Sc[row][vt] = exp(m_t - m_fin) / Z
__global__ __launch_bounds__(256) void stats_combine_kernel(
    const float* __restrict__ m_used, const float* __restrict__ Z_used,
    float* __restrict__ Sc) {
    const int row = blockIdx.x * 256 + threadIdx.x;
    float mv[NTC_];
    float m = -__builtin_inff();
#pragma unroll
    for (int i = 0; i < NTC_; i++) {
        mv[i] = m_used[(size_t)row * NTC_ + i];
        m = fmaxf(m, mv[i]);
    }
    float z = 0.f;
    float ev[NTC_];
#pragma unroll
    for (int i = 0; i < NTC_; i++) {
        ev[i] = __expf(mv[i] - m);
        z += Z_used[(size_t)row * NTC_ + i] * ev[i];
    }
    const float inv = 1.f / z;
#pragma unroll
    for (int i = 0; i < NTC_; i++) Sc[(size_t)row * NTC_ + i] = ev[i] * inv;
}

// ---------------------------------------------------------------------------
// K6: out = sum_vt Sc(row,vt) * (P'_vt @ V_vt). 128x128 tile, BK=64,
// 4 waves 2x2 of 64x64, gload_lds + swizzle, scale folded per v-tile.
__global__ __launch_bounds__(256, 2) void pv_gemm_kernel(
    const unsigned short* __restrict__ Pp, const unsigned short* __restrict__ VT,
    const float* __restrict__ Sc, float* __restrict__ Out) {
    __shared__ alignas(16) unsigned short sA[128 * 64], sB[128 * 64];
    const int b = blockIdx.z, bm = blockIdx.x, bn = blockIdx.y;
    const int t = threadIdx.x, lane = t & 63, w = t >> 6;
    const int wr = (w >> 1) * 64, wc = (w & 1) * 64;
    const int fr = lane & 15, fg = lane >> 4;

    size_t aog[4], bog[4];
    int dbs[4];
#pragma unroll
    for (int i = 0; i < 4; i++) {
        const int r = w * 32 + i * 8 + (lane >> 3);
        const int cg = (lane & 7) ^ (r & 7);
        aog[i] = ((size_t)b * LU_ + bm * 128 + r) * LV_ + cg * 8;
        bog[i] = ((size_t)b * D_ + bn * 128 + r) * LV_ + cg * 8;
        dbs[i] = (w * 32 + i * 8) * 64;
    }
    int aoff[2][4], boff[2][4];
#pragma unroll
    for (int kk = 0; kk < 2; kk++) {
#pragma unroll
        for (int m = 0; m < 4; m++) {
            const int r = wr + m * 16 + fr;
            aoff[kk][m] = r * 64 + (((kk * 4 + fg) ^ (r & 7))) * 8;
        }
#pragma unroll
        for (int n = 0; n < 4; n++) {
            const int r = wc + n * 16 + fr;
            boff[kk][n] = r * 64 + (((kk * 4 + fg) ^ (r & 7))) * 8;
        }
    }

    const f32x4 fzero = {0.f, 0.f, 0.f, 0.f};
    f32x4 acc[4][4];
#pragma unroll
    for (int m = 0; m < 4; m++)
#pragma unroll
        for (int n = 0; n < 4; n++) acc[m][n] = fzero;

    const int rowb = bm * 128 + wr + fg * 4;   // + m*16 + j

    for (int vt = 0; vt < 16; ++vt) {
        f32x4 part[4][4];
#pragma unroll
        for (int m = 0; m < 4; m++)
#pragma unroll
            for (int n = 0; n < 4; n++) part[m][n] = fzero;

#pragma unroll 1
        for (int kb = 0; kb < 2; ++kb) {
            const int k0 = vt * 128 + kb * 64;
            __syncthreads();
#pragma unroll
            for (int i = 0; i < 4; i++) {
                gload_lds16(Pp + aog[i] + k0, &sA[dbs[i]]);
                gload_lds16(VT + bog[i] + k0, &sB[dbs[i]]);
            }
            __syncthreads();
#pragma unroll
            for (int kk = 0; kk < 2; kk++) {
                bf16x8 af[4];
#pragma unroll
                for (int m = 0; m < 4; m++) af[m] = *(const bf16x8*)&sA[aoff[kk][m]];
#pragma unroll
                for (int n = 0; n < 4; n++) {
                    const bf16x8 bv = *(const bf16x8*)&sB[boff[kk][n]];
#pragma unroll
                    for (int m = 0; m < 4; m++)
                        part[m][n] = __builtin_amdgcn_mfma_f32_16x16x32_bf16(af[m], bv, part[m][n], 0, 0, 0);
                }
            }
        }
        float sc[4][4];
#pragma unroll
        for (int m = 0; m < 4; m++)
#pragma unroll
            for (int j = 0; j < 4; j++)
                sc[m][j] = Sc[((size_t)b * LU_ + rowb + m * 16 + j) * NTC_ + (vt >> 1)];
#pragma unroll
        for (int m = 0; m < 4; m++)
#pragma unroll
            for (int n = 0; n < 4; n++)
#pragma unroll
                for (int j = 0; j < 4; j++)
                    acc[m][n][j] += sc[m][j] * part[m][n][j];
    }

    float* Ob = Out + (size_t)b * LU_ * D_;
#pragma unroll
    for (int m = 0; m < 4; m++) {
        const int rbase = bm * 128 + wr + m * 16 + fg * 4;
#pragma unroll
        for (int n = 0; n < 4; n++) {
            const int col = bn * 128 + wc + n * 16 + fr;
#pragma unroll
            for (int j = 0; j < 4; j++)
                Ob[(size_t)(rbase + j) * D_ + col] = acc[m][n][j];
        }
    }
}

// ---------------------------------------------------------------------------
extern "C" void kernel_launch(void* const* d_in, const int* in_sizes, int n_in,
                              void* d_out, int out_size, void* d_ws, size_t ws_size,
                              hipStream_t stream) {
    (void)in_sizes; (void)n_in; (void)out_size; (void)ws_size;
    const float* u    = (const float*)d_in[0];
    const float* v    = (const float*)d_in[1];
    const void*  vm   = d_in[2];
    const float* W    = (const float*)d_in[3];
    const float* bias = (const float*)d_in[4];
    float* out = (float*)d_out;
    char* ws = (char*)d_ws;

    unsigned short* xs_hi = (unsigned short*)(ws + 0 * MB_);      // 64MB (transient)
    unsigned short* xs_lo = (unsigned short*)(ws + 64 * MB_);     // 64MB (transient)
    unsigned short* Pp    = (unsigned short*)(ws + 0 * MB_);      // 128MB (aliases xs)
    unsigned short* vT    = (unsigned short*)(ws + 128 * MB_);    // 64MB
    unsigned short* W_hi  = (unsigned short*)(ws + 192 * MB_);    // 2MB
    unsigned short* W_lo  = (unsigned short*)(ws + 194 * MB_);    // 2MB
    int*   lengths = (int*)(ws + 196 * MB_);
    float* m_used  = (float*)(ws + 197 * MB_);                    // 1MB
    float* Z_used  = (float*)(ws + 199 * MB_);                    // 1MB
    float* Sc      = (float*)(ws + 201 * MB_);                    // 1MB
    unsigned short* u_hi = (unsigned short*)(ws + 208 * MB_);     // 64MB
    unsigned short* u_lo = (unsigned short*)(ws + 272 * MB_);
    unsigned short* v_hi = (unsigned short*)(ws + 336 * MB_);
    unsigned short* v_lo = (unsigned short*)(ws + 400 * MB_);     // end 464MB

    const long nW8 = (long)D_ * D_ / 8;
    const long nX8 = (long)B_ * LU_ * D_ / 8;
    const size_t LDSB = 131072;   // 128 KiB dynamic LDS

    lengths_kernel<<<1, 256, 0, stream>>>(vm, lengths);
    split_kernel<<<512, 256, 0, stream>>>(W, W_hi, W_lo, nW8);
    split_kernel<<<4096, 256, 0, stream>>>(u, xs_hi, xs_lo, nX8);
    proj_kernel<<<dim3(B_ * LU_ / 256, D_ / 256), 512, LDSB, stream>>>(
        xs_hi, xs_lo, W_hi, W_lo, bias, u_hi, u_lo);
    split_kernel<<<4096, 256, 0, stream>>>(v, xs_hi, xs_lo, nX8);
    proj_kernel<<<dim3(B_ * LV_ / 256, D_ / 256), 512, LDSB, stream>>>(
        xs_hi, xs_lo, W_hi, W_lo, bias, v_hi, v_lo);
    transpose_v_kernel<<<dim3(LV_ / 64, D_ / 64, B_), 256, 0, stream>>>(v, vT);
    attn_logits_kernel<<<dim3(LU_ / 256, LV_ / 256, B_), 512, LDSB, stream>>>(
        u_hi, u_lo, v_hi, v_lo, lengths, Pp, m_used, Z_used);
    stats_combine_kernel<<<B_ * LU_ / 256, 256, 0, stream>>>(m_used, Z_used, Sc);
    pv_gemm_kernel<<<dim3(LU_ / 128, D_ / 128, B_), 256, 0, stream>>>(Pp, vT, Sc, out);
}